// Round 2
// baseline (575.534 us; speedup 1.0000x reference)
//
#include <hip/hip_runtime.h>
#include <hip/hip_bf16.h>

#define NHEAD 8
#define IMG   3136      // 56*56
#define NWINB 2592      // 32 * 9 * 9
#define MTOT  100352    // 32*3136

typedef __attribute__((ext_vector_type(2))) _Float16 f16x2;
typedef __attribute__((ext_vector_type(4))) float    f32x4;
typedef __attribute__((ext_vector_type(16))) float   f32x16;
typedef __attribute__((ext_vector_type(8))) short    bf16x8;
typedef __attribute__((ext_vector_type(4))) short    s16x4;
typedef __attribute__((ext_vector_type(4))) int      i32x4;

#define SWZ(byteoff, r) ((byteoff) ^ (((r)&7)<<4))
// stronger swizzle for 512B rows: row bits 0-2 -> byte bits 4-6, row bit 3 -> byte bit 7
#define SWZA(byteoff, r) ((byteoff) ^ (((r)&7)<<4) ^ ((((r)>>3)&1)<<7))

__device__ __forceinline__ short f2bf(float f){
  union { float fv; unsigned u; } a; a.fv = f;
  unsigned u = a.u;
  unsigned r = (u + 0x7fffu + ((u >> 16) & 1u)) >> 16;
  return (short)r;
}

__device__ __forceinline__ float dot2f16(f16x2 a, f16x2 b, float c){
#if __has_builtin(__builtin_amdgcn_fdot2)
  return __builtin_amdgcn_fdot2(a, b, c, false);
#else
  return c + (float)a[0]*(float)b[0] + (float)a[1]*(float)b[1];
#endif
}

// fast tanh-form GeLU (max abs dev from exact erf-GeLU ~3e-4)
__device__ __forceinline__ float gelu_f(float v){
  float u = v*(0.7978845608028654f + 0.0356774081f*(v*v));
  float e = __expf(2.f*u);
  float th = 1.f - 2.f/(e + 1.f);     // tanh(u), saturates correctly for e->inf/0
  return 0.5f*v*(1.f + th);
}

// ---------------- K0: weight prep ----------------
// blocks 0..63  : W1^T tiles (fc1_w 256x1024 -> w1t [1024][256] bf16)
// blocks 64..127: W2^T tiles (fc2_w 1024x256 -> w2t [256][1024] bf16)
// block 128     : spatial weight pack -> f16 j-pairs [h*49+i][25]
__global__ void prep_k(const float* __restrict__ fc1w, const float* __restrict__ fc2w,
                       const float* __restrict__ spw,
                       short* __restrict__ w1t, short* __restrict__ w2t,
                       f16x2* __restrict__ wsp)
{
  __shared__ float tl[64*65];
  int bid = blockIdx.x, t = threadIdx.x;
  if (bid < 64) {
    int kt = bid >> 4, nt = bid & 15;
    int k0 = kt*64, n0 = nt*64;
    for (int rep = 0; rep < 16; ++rep) {
      int row = rep*4 + (t>>6), col = t&63;
      tl[row*65+col] = fc1w[(size_t)(k0+row)*1024 + n0 + col];
    }
    __syncthreads();
    for (int rep = 0; rep < 16; ++rep) {
      int nr = rep*4 + (t>>6), kc = t&63;
      w1t[(size_t)(n0+nr)*256 + k0 + kc] = f2bf(tl[kc*65 + nr]);
    }
  } else if (bid < 128) {
    int id = bid - 64;
    int kt = id >> 2, nt = id & 3;
    int k0 = kt*64, n0 = nt*64;
    for (int rep = 0; rep < 16; ++rep) {
      int row = rep*4 + (t>>6), col = t&63;
      tl[row*65+col] = fc2w[(size_t)(k0+row)*256 + n0 + col];
    }
    __syncthreads();
    for (int rep = 0; rep < 16; ++rep) {
      int nr = rep*4 + (t>>6), kc = t&63;
      w2t[(size_t)(n0+nr)*1024 + k0 + kc] = f2bf(tl[kc*65 + nr]);
    }
  } else {
    for (int idx = t; idx < 9800; idx += 256) {
      int hi_ = idx/25, jp = idx - hi_*25;
      int j0 = jp*2;
      float lo = spw[hi_*49 + j0];
      float hi = (j0+1 < 49) ? spw[hi_*49 + j0 + 1] : 0.f;
      f16x2 v; v[0] = (_Float16)lo; v[1] = (_Float16)hi;
      wsp[idx] = v;
    }
  }
}

// ---------------- K1: LN1 + spatial window MLP + residual -> x1 (=d_out) ----------------
// one block per window (b, wi, wj). pad: top/left 4, bottom/right 3.
__global__ __launch_bounds__(256,2) void win_k(
    const float* __restrict__ x, const float* __restrict__ n1w, const float* __restrict__ n1b,
    const float* __restrict__ spb, const f16x2* __restrict__ wsp,
    float* __restrict__ x1)
{
  __shared__ _Float16 lx[25*256*2];   // [jp][c][2] f16, j-pairs; 25600 B
  __shared__ f16x2 lw[8*49*25];       // [h][i][jp]; 39200 B
  int t = threadIdx.x, lane = t & 63, wave = t >> 6;
  int bid = blockIdx.x;
  int b = bid/81, rem = bid - b*81, wi = rem/9, wj = rem - (rem/9)*9;

  // zero x-tile (covers padded positions + j=49 pad half)
  int* lxi = (int*)lx;
  for (int i = t; i < 6400; i += 256) lxi[i] = 0;
  // stage packed spatial weights
  for (int i = t; i < 9800; i += 256) lw[i] = wsp[i];
  __syncthreads();

  f32x4 wv = *(const f32x4*)(n1w + lane*4);
  f32x4 bv = *(const f32x4*)(n1b + lane*4);

  for (int i = wave; i < 49; i += 4) {
    int iy = i/7, ix = i - iy*7;
    int hh = wi*7 + iy - 4, ww = wj*7 + ix - 4;
    if (hh < 0 || hh >= 56 || ww < 0 || ww >= 56) continue;  // uniform per wave
    const float* row = x + ((size_t)(b*IMG + hh*56 + ww))*256;
    f32x4 v = *(const f32x4*)(row + lane*4);
    float s  = v[0]+v[1]+v[2]+v[3];
    float s2 = v[0]*v[0]+v[1]*v[1]+v[2]*v[2]+v[3]*v[3];
    #pragma unroll
    for (int m = 1; m < 64; m <<= 1) { s += __shfl_xor(s, m); s2 += __shfl_xor(s2, m); }
    float mu = s * (1.f/256.f);
    float var = s2 * (1.f/256.f) - mu*mu;
    float rs = rsqrtf(var + 1e-5f);
    int base = ((i>>1)*256 + lane*4)*2 + (i&1);
    #pragma unroll
    for (int q = 0; q < 4; ++q)
      lx[base + q*2] = (_Float16)(((v[q]-mu)*rs)*wv[q] + bv[q]);
  }
  __syncthreads();

  int c = t, h = t >> 5;
  const f16x2* wrow = lw + h*1225;    // [i][jp]
  float acc[49];
  #pragma unroll
  for (int i = 0; i < 49; ++i) acc[i] = 0.f;
  for (int jp = 0; jp < 25; ++jp) {
    f16x2 xp = *(const f16x2*)&lx[(jp*256 + c)*2];
    #pragma unroll
    for (int i = 0; i < 49; ++i)
      acc[i] = dot2f16(wrow[i*25 + jp], xp, acc[i]);
  }

  #pragma unroll
  for (int i = 0; i < 49; ++i) {
    int iy = i/7, ix = i - iy*7;
    int hh = wi*7 + iy - 4, ww = wj*7 + ix - 4;
    if (hh < 0 || hh >= 56 || ww < 0 || ww >= 56) continue;
    size_t off = ((size_t)(b*IMG + hh*56 + ww))*256 + c;
    x1[off] = x[off] + acc[i] + spb[h*49 + i];
  }
}

// ---------------- K2: fused LN2 + fc1 + GeLU + fc2 + residual (in-place on d_out) ----------------
// 784 blocks x 512 thr (8 waves, grid 2x4). LDS: a2[128][256]bf16 (64K) + hc[128][256]bf16 (64K).
// Weights read directly from global (L1/L2-hot). 32x32x16 MFMA. 9 barriers/block.
__global__ __launch_bounds__(512,2) void mlp_k(
    const float* __restrict__ x1, float* __restrict__ out,
    const short* __restrict__ w1t, const short* __restrict__ w2t,
    const float* __restrict__ n2w, const float* __restrict__ n2b,
    const float* __restrict__ b1, const float* __restrict__ b2)
{
  extern __shared__ char sm[];
  char* a2  = sm;                 // 65536: [128 rows][512 B] swizzled
  char* hcb = sm + 65536;         // 65536: [128 rows][512 B] swizzled

  int t = threadIdx.x, lane = t & 63, wave = t >> 6;
  int m0 = blockIdx.x * 128;

  // ---- Phase A: LN2 of 128 rows -> a2 (bf16, swizzled) ----
  {
    f32x4 nw = *(const f32x4*)(n2w + lane*4);
    f32x4 nb = *(const f32x4*)(n2b + lane*4);
    for (int rr = wave*16; rr < wave*16 + 16; ++rr) {
      f32x4 v = *(const f32x4*)(x1 + (size_t)(m0+rr)*256 + lane*4);
      float s  = v[0]+v[1]+v[2]+v[3];
      float s2 = v[0]*v[0]+v[1]*v[1]+v[2]*v[2]+v[3]*v[3];
      #pragma unroll
      for (int m = 1; m < 64; m <<= 1){ s += __shfl_xor(s,m); s2 += __shfl_xor(s2,m); }
      float mu = s*(1.f/256.f);
      float rs = rsqrtf(s2*(1.f/256.f) - mu*mu + 1e-5f);
      s16x4 pk;
      #pragma unroll
      for (int q = 0; q < 4; ++q) pk[q] = f2bf((v[q]-mu)*rs*nw[q] + nb[q]);
      *(s16x4*)(a2 + SWZA(lane*8, rr) + rr*512) = pk;
    }
  }
  __syncthreads();

  int wm = wave >> 2, wn = wave & 3;   // 2 row-halves x 4 col-quarters
  int lr = lane & 31, lk = lane >> 5;  // fragment row / k-chunk

  f32x16 accO[2][2];
  #pragma unroll
  for (int i=0;i<2;++i)
    #pragma unroll
    for (int j=0;j<2;++j)
      #pragma unroll
      for (int q=0;q<16;++q) accO[i][j][q] = 0.f;

  for (int ch = 0; ch < 4; ++ch) {
    // ---- GEMM1: accH[64m][64n] = a2[128][256] @ W1t-chunk^T ----
    f32x16 accH[2][2];
    #pragma unroll
    for (int i=0;i<2;++i)
      #pragma unroll
      for (int j=0;j<2;++j)
        #pragma unroll
        for (int q=0;q<16;++q) accH[i][j][q] = 0.f;

    const short* w1c = w1t + (size_t)(ch*256 + wn*64)*256;
    #pragma unroll
    for (int kk = 0; kk < 16; ++kk) {
      bf16x8 af[2], bf_[2];
      int kb = kk*32 + lk*16;          // byte offset of this lane's 8 bf16 k-slice
      #pragma unroll
      for (int ms = 0; ms < 2; ++ms) {
        int row = wm*64 + ms*32 + lr;
        af[ms] = *(const bf16x8*)(a2 + SWZA(kb, row) + row*512);
      }
      #pragma unroll
      for (int ns = 0; ns < 2; ++ns)
        bf_[ns] = *(const bf16x8*)(w1c + (size_t)(ns*32 + lr)*256 + kk*16 + lk*8);
      #pragma unroll
      for (int ms = 0; ms < 2; ++ms)
        #pragma unroll
        for (int ns = 0; ns < 2; ++ns)
          accH[ms][ns] = __builtin_amdgcn_mfma_f32_32x32x16_bf16(af[ms], bf_[ns], accH[ms][ns], 0,0,0);
    }

    // ---- bias + GeLU -> hc (bf16, swizzled) ----
    #pragma unroll
    for (int ns = 0; ns < 2; ++ns) {
      float b1v = b1[ch*256 + wn*64 + ns*32 + lr];
      #pragma unroll
      for (int ms = 0; ms < 2; ++ms) {
        #pragma unroll
        for (int r = 0; r < 16; ++r) {
          int rowl = wm*64 + ms*32 + (r&3) + 8*(r>>2) + 4*lk;
          int colb = (wn*64 + ns*32 + lr)*2;
          float g = gelu_f(accH[ms][ns][r] + b1v);
          *(short*)(hcb + SWZA(colb, rowl) + rowl*512) = f2bf(g);
        }
      }
    }
    __syncthreads();

    // ---- GEMM2: accO[64m][64n] += hc[128][256] @ W2t-chunk^T ----
    const short* w2c = w2t + (size_t)(wn*64)*1024 + ch*256;
    #pragma unroll
    for (int kk = 0; kk < 16; ++kk) {
      bf16x8 af[2], bf_[2];
      int kb = kk*32 + lk*16;
      #pragma unroll
      for (int ms = 0; ms < 2; ++ms) {
        int row = wm*64 + ms*32 + lr;
        af[ms] = *(const bf16x8*)(hcb + SWZA(kb, row) + row*512);
      }
      #pragma unroll
      for (int ns = 0; ns < 2; ++ns)
        bf_[ns] = *(const bf16x8*)(w2c + (size_t)(ns*32 + lr)*1024 + kk*16 + lk*8);
      #pragma unroll
      for (int ms = 0; ms < 2; ++ms)
        #pragma unroll
        for (int ns = 0; ns < 2; ++ns)
          accO[ms][ns] = __builtin_amdgcn_mfma_f32_32x32x16_bf16(af[ms], bf_[ns], accO[ms][ns], 0,0,0);
    }
    __syncthreads();   // protect hc before next chunk overwrites
  }

  // ---- epilogue: out = x1 + accO + b2 (coalesced: 32 consecutive cols/lane-group) ----
  #pragma unroll
  for (int ns = 0; ns < 2; ++ns) {
    int col = wn*64 + ns*32 + lr;
    float b2v = b2[col];
    #pragma unroll
    for (int ms = 0; ms < 2; ++ms) {
      #pragma unroll
      for (int r = 0; r < 16; ++r) {
        int row = wm*64 + ms*32 + (r&3) + 8*(r>>2) + 4*lk;
        size_t off = (size_t)(m0 + row)*256 + col;
        out[off] = x1[off] + accO[ms][ns][r] + b2v;
      }
    }
  }
}

extern "C" void kernel_launch(void* const* d_in, const int* in_sizes, int n_in,
                              void* d_out, int out_size, void* d_ws, size_t ws_size,
                              hipStream_t stream) {
  const float* x    = (const float*)d_in[0];
  const float* n1w  = (const float*)d_in[1];
  const float* n1b  = (const float*)d_in[2];
  const float* spw  = (const float*)d_in[3];
  const float* spb  = (const float*)d_in[4];
  const float* n2w  = (const float*)d_in[5];
  const float* n2b  = (const float*)d_in[6];
  const float* fc1w = (const float*)d_in[7];
  const float* fc1b = (const float*)d_in[8];
  const float* fc2w = (const float*)d_in[9];
  const float* fc2b = (const float*)d_in[10];
  float* outp = (float*)d_out;

  char* ws = (char*)d_ws;
  short* w1t = (short*)ws;                    // [1024][256] bf16 : 524288 B
  short* w2t = (short*)(ws + 524288);         // [256][1024] bf16 : 524288 B
  f16x2* wsp = (f16x2*)(ws + 1048576);        // [392][25] f16x2  : 39200 B

  prep_k<<<129, 256, 0, stream>>>(fc1w, fc2w, spw, w1t, w2t, wsp);
  win_k<<<NWINB, 256, 0, stream>>>(x, n1w, n1b, spb, wsp, outp);
  hipFuncSetAttribute(reinterpret_cast<const void*>(mlp_k),
                      hipFuncAttributeMaxDynamicSharedMemorySize, 131072);
  mlp_k<<<MTOT/128, 512, 131072, stream>>>(outp, outp, w1t, w2t, n2w, n2b, fc1b, fc2b);
}

// Round 4
// 502.959 us; speedup vs baseline: 1.1443x; 1.1443x over previous
//
#include <hip/hip_runtime.h>
#include <hip/hip_bf16.h>

#define NHEAD 8
#define IMG   3136      // 56*56
#define MTOT  100352    // 32*3136

typedef __attribute__((ext_vector_type(2))) _Float16 f16x2;
typedef __attribute__((ext_vector_type(8))) _Float16 f16x8;
typedef __attribute__((ext_vector_type(4))) float    f32x4;
typedef __attribute__((ext_vector_type(16))) float   f32x16;
typedef __attribute__((ext_vector_type(8))) short    bf16x8;
typedef __attribute__((ext_vector_type(4))) short    s16x4;

// swizzle for 512B rows: row bits 0-2 -> byte bits 4-6, row bit 3 -> byte bit 7
#define SWZA(byteoff, r) ((byteoff) ^ (((r)&7)<<4) ^ ((((r)>>3)&1)<<7))

__device__ __forceinline__ short f2bf(float f){
  union { float fv; unsigned u; } a; a.fv = f;
  unsigned u = a.u;
  unsigned r = (u + 0x7fffu + ((u >> 16) & 1u)) >> 16;
  return (short)r;
}

__device__ __forceinline__ float dot2f16(f16x2 a, f16x2 b, float c){
#if __has_builtin(__builtin_amdgcn_fdot2)
  return __builtin_amdgcn_fdot2(a, b, c, false);
#else
  return c + (float)a[0]*(float)b[0] + (float)a[1]*(float)b[1];
#endif
}

// fast tanh-form GeLU (max abs dev from exact erf-GeLU ~3e-4)
__device__ __forceinline__ float gelu_f(float v){
  float u = v*(0.7978845608028654f + 0.0356774081f*(v*v));
  float e = __expf(2.f*u);
  float th = 1.f - 2.f/(e + 1.f);
  return 0.5f*v*(1.f + th);
}

// ---------------- K0: weight prep ----------------
// blocks 0..127  : w1p fragment-packed  (fc1_w [256][1024] -> [(f*16+kk)*64+lane][8] bf16)
// blocks 128..255: w2p fragment-packed  (fc2_w [1024][256] -> [(f*64+kk)*64+lane][8] bf16)
// block 256      : spatial weight pack -> [h][jpp(25)][i(52 pad)] f16x2 of (j=2jpp, 2jpp+1)
__global__ void prep_k(const float* __restrict__ fc1w, const float* __restrict__ fc2w,
                       const float* __restrict__ spw,
                       short* __restrict__ w1p, short* __restrict__ w2p,
                       f16x2* __restrict__ wsp2)
{
  int bid = blockIdx.x, t = threadIdx.x;
  if (bid < 128) {
    int id = bid*256 + t;            // [0, 32768)
    int l = id & 63, fk = id >> 6;   // fk = f*16+kk
    int kk = fk & 15, f = fk >> 4;
    int n = f*32 + (l & 31);
    int kbase = kk*16 + (l >> 5)*8;
    bf16x8 o;
    #pragma unroll
    for (int e = 0; e < 8; ++e) o[e] = f2bf(fc1w[(size_t)(kbase+e)*1024 + n]);
    *(bf16x8*)(w1p + (size_t)id*8) = o;
  } else if (bid < 256) {
    int id = (bid-128)*256 + t;      // [0, 32768)
    int l = id & 63, fk = id >> 6;   // fk = f*64+kk
    int kk = fk & 63, f = fk >> 6;
    int n = f*32 + (l & 31);
    int kbase = kk*16 + (l >> 5)*8;
    bf16x8 o;
    #pragma unroll
    for (int e = 0; e < 8; ++e) o[e] = f2bf(fc2w[(size_t)(kbase+e)*256 + n]);
    *(bf16x8*)(w2p + (size_t)id*8) = o;
  } else {
    // 8 heads * 25 jpp * 52 i-slots
    for (int idx = t; idx < 8*25*52; idx += 256) {
      int h = idx / 1300, rem = idx - h*1300;
      int jpp = rem / 52, i = rem - jpp*52;
      float lo = 0.f, hi = 0.f;
      if (i < 49) {
        int j0 = jpp*2;
        lo = spw[(size_t)(h*49 + i)*49 + j0];
        if (j0 + 1 < 49) hi = spw[(size_t)(h*49 + i)*49 + j0 + 1];
      }
      f16x2 v; v[0] = (_Float16)lo; v[1] = (_Float16)hi;
      wsp2[idx] = v;
    }
  }
}

// ---------------- K1: LN1 + spatial window MLP + residual -> x1 (=d_out) ----------------
// 648 blocks x 512 thr; 4 windows/block; wave = head; thread handles 2 windows (shared weights).
// LDS: lx [4 win][25 jpp][256 c] f16x2 = 102400 ; lw [8 h][25 jpp][52 i] f16x2 = 41600
__global__ __launch_bounds__(512,2) void win_k(
    const float* __restrict__ x, const float* __restrict__ n1w, const float* __restrict__ n1b,
    const float* __restrict__ spb, const f16x2* __restrict__ wsp2,
    float* __restrict__ x1)
{
  extern __shared__ char wsm[];
  char* lx = wsm;                 // 102400
  char* lw = wsm + 102400;        // 41600
  int t = threadIdx.x, lane = t & 63, wave = t >> 6;
  int bid = blockIdx.x;

  int wi_[4], wj_[4], b_[4];
  #pragma unroll
  for (int w = 0; w < 4; ++w) {
    int win = bid*4 + w;
    b_[w] = win/81; int rem = win - b_[w]*81;
    wi_[w] = rem/9; wj_[w] = rem - (rem/9)*9;
  }

  int* lxi = (int*)lx;
  for (int i = t; i < 25600; i += 512) lxi[i] = 0;
  const int* wg = (const int*)wsp2;
  int* lwi = (int*)lw;
  for (int i = t; i < 10400; i += 512) lwi[i] = wg[i];
  __syncthreads();

  // LN phase: 4 windows x 49 rows over 8 waves
  f32x4 wv = *(const f32x4*)(n1w + lane*4);
  f32x4 bv = *(const f32x4*)(n1b + lane*4);
  #pragma unroll
  for (int w = 0; w < 4; ++w) {
    for (int i = wave; i < 49; i += 8) {
      int iy = i/7, ix = i - iy*7;
      int hh = wi_[w]*7 + iy - 4, ww = wj_[w]*7 + ix - 4;
      if (hh < 0 || hh >= 56 || ww < 0 || ww >= 56) continue;  // wave-uniform
      const float* row = x + ((size_t)(b_[w]*IMG + hh*56 + ww))*256;
      f32x4 v = *(const f32x4*)(row + lane*4);
      float s  = v[0]+v[1]+v[2]+v[3];
      float s2 = v[0]*v[0]+v[1]*v[1]+v[2]*v[2]+v[3]*v[3];
      #pragma unroll
      for (int m = 1; m < 64; m <<= 1) { s += __shfl_xor(s, m); s2 += __shfl_xor(s2, m); }
      float mu = s * (1.f/256.f);
      float rs = rsqrtf(s2*(1.f/256.f) - mu*mu + 1e-5f);
      char* base = lx + w*25600 + (i>>1)*1024 + (i&1)*2;
      #pragma unroll
      for (int q = 0; q < 4; ++q)
        *(_Float16*)(base + (lane*4+q)*4) = (_Float16)(((v[q]-mu)*rs)*wv[q] + bv[q]);
    }
  }
  __syncthreads();

  // dot phase: wave = head h; lanes 0-31 -> windows 0,1 ; lanes 32-63 -> windows 2,3
  int h = __builtin_amdgcn_readfirstlane(wave);
  int d = lane & 31;
  int hw = lane >> 5;
  int wA = hw*2, wB = hw*2 + 1;
  int c = h*32 + d;
  const char* lxA = lx + wA*25600 + c*4;
  const char* lxB = lx + wB*25600 + c*4;
  const char* lwh = lw + h*5200;        // 25 jpp * 52 i * 4 B per head

  float accA[52], accB[52];
  #pragma unroll
  for (int i = 0; i < 52; ++i) { accA[i] = 0.f; accB[i] = 0.f; }

  for (int jpp = 0; jpp < 25; ++jpp) {
    f16x2 xa = *(const f16x2*)(lxA + jpp*1024);
    f16x2 xb = *(const f16x2*)(lxB + jpp*1024);
    const char* wrow = lwh + jpp*208;
    #pragma unroll
    for (int ib = 0; ib < 13; ++ib) {
      f16x8 wq = *(const f16x8*)(wrow + ib*16);
      #pragma unroll
      for (int q = 0; q < 4; ++q) {
        f16x2 wp; wp[0] = wq[2*q]; wp[1] = wq[2*q+1];
        accA[ib*4+q] = dot2f16(wp, xa, accA[ib*4+q]);
        accB[ib*4+q] = dot2f16(wp, xb, accB[ib*4+q]);
      }
    }
  }

  // epilogue: residual + bias, scatter stores (half-wave 128B contiguous)
  int winA = bid*4 + wA; int bA = winA/81, remA = winA - bA*81, wiA = remA/9, wjA = remA - (remA/9)*9;
  int winB = bid*4 + wB; int bB = winB/81, remB = winB - bB*81, wiB = remB/9, wjB = remB - (remB/9)*9;
  #pragma unroll
  for (int i = 0; i < 49; ++i) {
    int iy = i/7, ix = i - iy*7;
    float sb = spb[h*49 + i];
    {
      int hh = wiA*7 + iy - 4, ww = wjA*7 + ix - 4;
      if (hh >= 0 && hh < 56 && ww >= 0 && ww < 56) {
        size_t off = ((size_t)(bA*IMG + hh*56 + ww))*256 + c;
        x1[off] = x[off] + accA[i] + sb;
      }
    }
    {
      int hh = wiB*7 + iy - 4, ww = wjB*7 + ix - 4;
      if (hh >= 0 && hh < 56 && ww >= 0 && ww < 56) {
        size_t off = ((size_t)(bB*IMG + hh*56 + ww))*256 + c;
        x1[off] = x[off] + accB[i] + sb;
      }
    }
  }
}

// ---------------- K2: fused LN2 + fc1 + GeLU + fc2 + residual (in-place on d_out) ----------------
// 784 blocks x 512 thr (8 waves, 2x4). LDS: a2[128][512B] + hc[128][512B], both swizzled.
// Weights read directly from global in MFMA-fragment-packed order (coalesced 1KB/frag).
__global__ __launch_bounds__(512,2) void mlp_k(
    const float* __restrict__ x1, float* __restrict__ out,
    const short* __restrict__ w1p, const short* __restrict__ w2p,
    const float* __restrict__ n2w, const float* __restrict__ n2b,
    const float* __restrict__ b1, const float* __restrict__ b2)
{
  extern __shared__ char sm[];
  char* a2  = sm;                 // 65536
  char* hcb = sm + 65536;         // 65536

  int t = threadIdx.x, lane = t & 63, wave = t >> 6;
  int m0 = blockIdx.x * 128;

  // ---- Phase A: LN2 of 128 rows -> a2 (bf16, swizzled) ----
  {
    f32x4 nw = *(const f32x4*)(n2w + lane*4);
    f32x4 nb = *(const f32x4*)(n2b + lane*4);
    for (int rr = wave*16; rr < wave*16 + 16; ++rr) {
      f32x4 v = *(const f32x4*)(x1 + (size_t)(m0+rr)*256 + lane*4);
      float s  = v[0]+v[1]+v[2]+v[3];
      float s2 = v[0]*v[0]+v[1]*v[1]+v[2]*v[2]+v[3]*v[3];
      #pragma unroll
      for (int m = 1; m < 64; m <<= 1){ s += __shfl_xor(s,m); s2 += __shfl_xor(s2,m); }
      float mu = s*(1.f/256.f);
      float rs = rsqrtf(s2*(1.f/256.f) - mu*mu + 1e-5f);
      s16x4 pk;
      #pragma unroll
      for (int q = 0; q < 4; ++q) pk[q] = f2bf((v[q]-mu)*rs*nw[q] + nb[q]);
      *(s16x4*)(a2 + SWZA(lane*8, rr) + rr*512) = pk;
    }
  }
  __syncthreads();

  int wm = wave >> 2, wn = wave & 3;
  int lr = lane & 31, lk = lane >> 5;

  f32x16 accO[2][2];
  #pragma unroll
  for (int i=0;i<2;++i)
    #pragma unroll
    for (int j=0;j<2;++j)
      #pragma unroll
      for (int q=0;q<16;++q) accO[i][j][q] = 0.f;

  for (int ch = 0; ch < 4; ++ch) {
    f32x16 accH[2][2];
    #pragma unroll
    for (int i=0;i<2;++i)
      #pragma unroll
      for (int j=0;j<2;++j)
        #pragma unroll
        for (int q=0;q<16;++q) accH[i][j][q] = 0.f;

    // ---- GEMM1: fragment-packed B, coalesced lane*16B loads ----
    const short* w1f0 = w1p + ((size_t)((ch*8 + wn*2 + 0)*16)*64 + lane)*8;
    const short* w1f1 = w1p + ((size_t)((ch*8 + wn*2 + 1)*16)*64 + lane)*8;
    #pragma unroll
    for (int kk = 0; kk < 16; ++kk) {
      bf16x8 af[2], bf0, bf1;
      int kb = kk*32 + lk*16;
      #pragma unroll
      for (int ms = 0; ms < 2; ++ms) {
        int row = wm*64 + ms*32 + lr;
        af[ms] = *(const bf16x8*)(a2 + SWZA(kb, row) + row*512);
      }
      bf0 = *(const bf16x8*)(w1f0 + kk*512);
      bf1 = *(const bf16x8*)(w1f1 + kk*512);
      #pragma unroll
      for (int ms = 0; ms < 2; ++ms) {
        accH[ms][0] = __builtin_amdgcn_mfma_f32_32x32x16_bf16(af[ms], bf0, accH[ms][0], 0,0,0);
        accH[ms][1] = __builtin_amdgcn_mfma_f32_32x32x16_bf16(af[ms], bf1, accH[ms][1], 0,0,0);
      }
    }

    // ---- bias + GeLU -> hc (bf16, swizzled) ----
    #pragma unroll
    for (int ns = 0; ns < 2; ++ns) {
      float b1v = b1[ch*256 + wn*64 + ns*32 + lr];
      #pragma unroll
      for (int ms = 0; ms < 2; ++ms) {
        #pragma unroll
        for (int r = 0; r < 16; ++r) {
          int rowl = wm*64 + ms*32 + (r&3) + 8*(r>>2) + 4*lk;
          int colb = (wn*64 + ns*32 + lr)*2;
          float g = gelu_f(accH[ms][ns][r] + b1v);
          *(short*)(hcb + SWZA(colb, rowl) + rowl*512) = f2bf(g);
        }
      }
    }
    __syncthreads();

    // ---- GEMM2: fragment-packed B ----
    const short* w2f0 = w2p + ((size_t)((wn*2 + 0)*64 + ch*16)*64 + lane)*8;
    const short* w2f1 = w2p + ((size_t)((wn*2 + 1)*64 + ch*16)*64 + lane)*8;
    #pragma unroll
    for (int kk = 0; kk < 16; ++kk) {
      bf16x8 af[2], bf0, bf1;
      int kb = kk*32 + lk*16;
      #pragma unroll
      for (int ms = 0; ms < 2; ++ms) {
        int row = wm*64 + ms*32 + lr;
        af[ms] = *(const bf16x8*)(hcb + SWZA(kb, row) + row*512);
      }
      bf0 = *(const bf16x8*)(w2f0 + kk*512);
      bf1 = *(const bf16x8*)(w2f1 + kk*512);
      #pragma unroll
      for (int ms = 0; ms < 2; ++ms) {
        accO[ms][0] = __builtin_amdgcn_mfma_f32_32x32x16_bf16(af[ms], bf0, accO[ms][0], 0,0,0);
        accO[ms][1] = __builtin_amdgcn_mfma_f32_32x32x16_bf16(af[ms], bf1, accO[ms][1], 0,0,0);
      }
    }
    __syncthreads();
  }

  // ---- epilogue: out = x1 + accO + b2 ----
  #pragma unroll
  for (int ns = 0; ns < 2; ++ns) {
    int col = wn*64 + ns*32 + lr;
    float b2v = b2[col];
    #pragma unroll
    for (int ms = 0; ms < 2; ++ms) {
      #pragma unroll
      for (int r = 0; r < 16; ++r) {
        int row = wm*64 + ms*32 + (r&3) + 8*(r>>2) + 4*lk;
        size_t off = (size_t)(m0 + row)*256 + col;
        out[off] = x1[off] + accO[ms][ns][r] + b2v;
      }
    }
  }
}

extern "C" void kernel_launch(void* const* d_in, const int* in_sizes, int n_in,
                              void* d_out, int out_size, void* d_ws, size_t ws_size,
                              hipStream_t stream) {
  const float* x    = (const float*)d_in[0];
  const float* n1w  = (const float*)d_in[1];
  const float* n1b  = (const float*)d_in[2];
  const float* spw  = (const float*)d_in[3];
  const float* spb  = (const float*)d_in[4];
  const float* n2w  = (const float*)d_in[5];
  const float* n2b  = (const float*)d_in[6];
  const float* fc1w = (const float*)d_in[7];
  const float* fc1b = (const float*)d_in[8];
  const float* fc2w = (const float*)d_in[9];
  const float* fc2b = (const float*)d_in[10];
  float* outp = (float*)d_out;

  char* ws = (char*)d_ws;
  short* w1p = (short*)ws;                    // 524288 B
  short* w2p = (short*)(ws + 524288);         // 524288 B
  f16x2* wsp2 = (f16x2*)(ws + 1048576);       // 8*25*52*4 = 41600 B

  prep_k<<<257, 256, 0, stream>>>(fc1w, fc2w, spw, w1p, w2p, wsp2);

  hipFuncSetAttribute(reinterpret_cast<const void*>(win_k),
                      hipFuncAttributeMaxDynamicSharedMemorySize, 144000);
  win_k<<<648, 512, 144000, stream>>>(x, n1w, n1b, spb, wsp2, outp);

  hipFuncSetAttribute(reinterpret_cast<const void*>(mlp_k),
                      hipFuncAttributeMaxDynamicSharedMemorySize, 131072);
  mlp_k<<<MTOT/128, 512, 131072, stream>>>(outp, outp, w1p, w2p, n2w, n2b, fc1b, fc2b);
}

// Round 5
// 378.902 us; speedup vs baseline: 1.5190x; 1.3274x over previous
//
#include <hip/hip_runtime.h>
#include <hip/hip_bf16.h>

#define NHEAD 8
#define IMG   3136      // 56*56
#define MTOT  100352    // 32*3136

typedef __attribute__((ext_vector_type(2))) _Float16 f16x2;
typedef __attribute__((ext_vector_type(8))) _Float16 f16x8;
typedef __attribute__((ext_vector_type(4))) float    f32x4;
typedef __attribute__((ext_vector_type(16))) float   f32x16;
typedef __attribute__((ext_vector_type(8))) short    bf16x8;
typedef __attribute__((ext_vector_type(4))) short    s16x4;
typedef __attribute__((ext_vector_type(4))) int      i32x4;

// swizzle for 512B rows: row bits 0-2 -> byte bits 4-6, row bit 3 -> byte bit 7
#define SWZA(byteoff, r) ((byteoff) ^ (((r)&7)<<4) ^ ((((r)>>3)&1)<<7))

__device__ __forceinline__ short f2bf(float f){
  union { float fv; unsigned u; } a; a.fv = f;
  unsigned u = a.u;
  unsigned r = (u + 0x7fffu + ((u >> 16) & 1u)) >> 16;
  return (short)r;
}

__device__ __forceinline__ float dot2f16(f16x2 a, f16x2 b, float c){
#if __has_builtin(__builtin_amdgcn_fdot2)
  return __builtin_amdgcn_fdot2(a, b, c, false);
#else
  return c + (float)a[0]*(float)b[0] + (float)a[1]*(float)b[1];
#endif
}

// fast tanh-form GeLU (max abs dev from exact erf-GeLU ~3e-4)
__device__ __forceinline__ float gelu_f(float v){
  float u = v*(0.7978845608028654f + 0.0356774081f*(v*v));
  float e = __expf(2.f*u);
  float th = 1.f - 2.f/(e + 1.f);
  return 0.5f*v*(1.f + th);
}

// ---------------- K0: weight prep ----------------
// blocks 0..127  : w1p fragment-packed  (fc1_w [256][1024] -> [(f*16+kk)*64+lane][8] bf16)
// blocks 128..255: w2p fragment-packed  (fc2_w [1024][256] -> [(f*64+kk)*64+lane][8] bf16)
// block 256      : spatial weight pack -> [h][jpp(25)][i(52 pad)] f16x2 of (j=2jpp, 2jpp+1)
__global__ void prep_k(const float* __restrict__ fc1w, const float* __restrict__ fc2w,
                       const float* __restrict__ spw,
                       short* __restrict__ w1p, short* __restrict__ w2p,
                       f16x2* __restrict__ wsp2)
{
  int bid = blockIdx.x, t = threadIdx.x;
  if (bid < 128) {
    int id = bid*256 + t;            // [0, 32768)
    int l = id & 63, fk = id >> 6;   // fk = f*16+kk
    int kk = fk & 15, f = fk >> 4;
    int n = f*32 + (l & 31);
    int kbase = kk*16 + (l >> 5)*8;
    bf16x8 o;
    #pragma unroll
    for (int e = 0; e < 8; ++e) o[e] = f2bf(fc1w[(size_t)(kbase+e)*1024 + n]);
    *(bf16x8*)(w1p + (size_t)id*8) = o;
  } else if (bid < 256) {
    int id = (bid-128)*256 + t;      // [0, 32768)
    int l = id & 63, fk = id >> 6;   // fk = f*64+kk
    int kk = fk & 63, f = fk >> 6;
    int n = f*32 + (l & 31);
    int kbase = kk*16 + (l >> 5)*8;
    bf16x8 o;
    #pragma unroll
    for (int e = 0; e < 8; ++e) o[e] = f2bf(fc2w[(size_t)(kbase+e)*256 + n]);
    *(bf16x8*)(w2p + (size_t)id*8) = o;
  } else {
    // 8 heads * 25 jpp * 52 i-slots
    for (int idx = t; idx < 8*25*52; idx += 256) {
      int h = idx / 1300, rem = idx - h*1300;
      int jpp = rem / 52, i = rem - jpp*52;
      float lo = 0.f, hi = 0.f;
      if (i < 49) {
        int j0 = jpp*2;
        lo = spw[(size_t)(h*49 + i)*49 + j0];
        if (j0 + 1 < 49) hi = spw[(size_t)(h*49 + i)*49 + j0 + 1];
      }
      f16x2 v; v[0] = (_Float16)lo; v[1] = (_Float16)hi;
      wsp2[idx] = v;
    }
  }
}

// ---------------- K1: LN1 + spatial window MLP + residual -> x1 (=d_out) ----------------
// 648 blocks x 512 thr; 4 windows/block; wave = head; thread handles 2 windows.
// Weights read via wave-uniform pointer straight from global (scalar K$ loads).
// LDS: lx [4 win][25 jpp][256 c] f16x2 = 102400 B only.
__global__ __launch_bounds__(512,2) void win_k(
    const float* __restrict__ x, const float* __restrict__ n1w, const float* __restrict__ n1b,
    const float* __restrict__ spb, const f16x2* __restrict__ wsp2,
    float* __restrict__ x1)
{
  extern __shared__ char wsm[];
  char* lx = wsm;                 // 102400
  int t = threadIdx.x, lane = t & 63, wave = t >> 6;
  int bid = blockIdx.x;

  int wi_[4], wj_[4], b_[4];
  #pragma unroll
  for (int w = 0; w < 4; ++w) {
    int win = bid*4 + w;
    b_[w] = win/81; int rem = win - b_[w]*81;
    wi_[w] = rem/9; wj_[w] = rem - (rem/9)*9;
  }

  // zero x-tile (covers padded positions + j=49 pad half)
  {
    i32x4 z4 = {0,0,0,0};
    i32x4* lx4 = (i32x4*)lx;
    for (int i = t; i < 6400; i += 512) lx4[i] = z4;
  }
  __syncthreads();

  // LN phase: 4 windows x 49 rows over 8 waves
  f32x4 wv = *(const f32x4*)(n1w + lane*4);
  f32x4 bv = *(const f32x4*)(n1b + lane*4);
  #pragma unroll
  for (int w = 0; w < 4; ++w) {
    for (int i = wave; i < 49; i += 8) {
      int iy = i/7, ix = i - iy*7;
      int hh = wi_[w]*7 + iy - 4, ww = wj_[w]*7 + ix - 4;
      if (hh < 0 || hh >= 56 || ww < 0 || ww >= 56) continue;  // wave-uniform
      const float* row = x + ((size_t)(b_[w]*IMG + hh*56 + ww))*256;
      f32x4 v = *(const f32x4*)(row + lane*4);
      float s  = v[0]+v[1]+v[2]+v[3];
      float s2 = v[0]*v[0]+v[1]*v[1]+v[2]*v[2]+v[3]*v[3];
      #pragma unroll
      for (int m = 1; m < 64; m <<= 1) { s += __shfl_xor(s, m); s2 += __shfl_xor(s2, m); }
      float mu = s * (1.f/256.f);
      float rs = rsqrtf(s2*(1.f/256.f) - mu*mu + 1e-5f);
      char* base = lx + w*25600 + (i>>1)*1024 + (i&1)*2;
      #pragma unroll
      for (int q = 0; q < 4; ++q)
        *(_Float16*)(base + (lane*4+q)*4) = (_Float16)(((v[q]-mu)*rs)*wv[q] + bv[q]);
    }
  }
  __syncthreads();

  // dot phase: wave = head h (uniform); lanes 0-31 -> windows 0,1 ; lanes 32-63 -> windows 2,3
  int h = __builtin_amdgcn_readfirstlane(wave);
  int d = lane & 31;
  int hw = lane >> 5;
  int wA = hw*2, wB = hw*2 + 1;
  int c = h*32 + d;
  const char* lxA = lx + wA*25600 + c*4;
  const char* lxB = lx + wB*25600 + c*4;
  const char* wgh = (const char*)wsp2 + h*5200;   // uniform -> scalar loads

  float accA[52], accB[52];
  #pragma unroll
  for (int i = 0; i < 52; ++i) { accA[i] = 0.f; accB[i] = 0.f; }

  for (int jpp = 0; jpp < 25; ++jpp) {
    f16x2 xa = *(const f16x2*)(lxA + jpp*1024);
    f16x2 xb = *(const f16x2*)(lxB + jpp*1024);
    const char* wrow = wgh + jpp*208;
    #pragma unroll
    for (int ib = 0; ib < 13; ++ib) {
      f16x8 wq = *(const f16x8*)(wrow + ib*16);
      #pragma unroll
      for (int q = 0; q < 4; ++q) {
        f16x2 wp; wp[0] = wq[2*q]; wp[1] = wq[2*q+1];
        accA[ib*4+q] = dot2f16(wp, xa, accA[ib*4+q]);
        accB[ib*4+q] = dot2f16(wp, xb, accB[ib*4+q]);
      }
    }
  }

  // epilogue: residual + bias
  int winA = bid*4 + wA; int bA = winA/81, remA = winA - bA*81, wiA = remA/9, wjA = remA - (remA/9)*9;
  int winB = bid*4 + wB; int bB = winB/81, remB = winB - bB*81, wiB = remB/9, wjB = remB - (remB/9)*9;
  #pragma unroll
  for (int i = 0; i < 49; ++i) {
    int iy = i/7, ix = i - iy*7;
    float sb = spb[h*49 + i];
    {
      int hh = wiA*7 + iy - 4, ww = wjA*7 + ix - 4;
      if (hh >= 0 && hh < 56 && ww >= 0 && ww < 56) {
        size_t off = ((size_t)(bA*IMG + hh*56 + ww))*256 + c;
        x1[off] = x[off] + accA[i] + sb;
      }
    }
    {
      int hh = wiB*7 + iy - 4, ww = wjB*7 + ix - 4;
      if (hh >= 0 && hh < 56 && ww >= 0 && ww < 56) {
        size_t off = ((size_t)(bB*IMG + hh*56 + ww))*256 + c;
        x1[off] = x[off] + accB[i] + sb;
      }
    }
  }
}

// ---------------- K2: fused LN2 + fc1 + GeLU + fc2 + residual (in-place on d_out) ----------------
// 1568 blocks x 512 thr (8 waves). 64-row tile. LDS: a2[64][512B] + hc[64][512B] = 64 KB
// -> 2 blocks/CU. Per wave: 64 rows x 32 cols, 1 B-frag/kk, depth-4 register prefetch.
__global__ __launch_bounds__(512,4) void mlp_k(
    const float* __restrict__ x1, float* __restrict__ out,
    const short* __restrict__ w1p, const short* __restrict__ w2p,
    const float* __restrict__ n2w, const float* __restrict__ n2b,
    const float* __restrict__ b1, const float* __restrict__ b2)
{
  extern __shared__ char sm[];
  char* a2  = sm;                 // 32768
  char* hcb = sm + 32768;         // 32768

  int t = threadIdx.x, lane = t & 63, wave = t >> 6;
  int m0 = blockIdx.x * 64;

  // ---- Phase A: LN2 of 64 rows -> a2 (bf16, swizzled) ----
  {
    f32x4 nw = *(const f32x4*)(n2w + lane*4);
    f32x4 nb = *(const f32x4*)(n2b + lane*4);
    #pragma unroll
    for (int rq = 0; rq < 8; ++rq) {
      int rr = wave*8 + rq;
      f32x4 v = *(const f32x4*)(x1 + (size_t)(m0+rr)*256 + lane*4);
      float s  = v[0]+v[1]+v[2]+v[3];
      float s2 = v[0]*v[0]+v[1]*v[1]+v[2]*v[2]+v[3]*v[3];
      #pragma unroll
      for (int m = 1; m < 64; m <<= 1){ s += __shfl_xor(s,m); s2 += __shfl_xor(s2,m); }
      float mu = s*(1.f/256.f);
      float rs = rsqrtf(s2*(1.f/256.f) - mu*mu + 1e-5f);
      s16x4 pk;
      #pragma unroll
      for (int q = 0; q < 4; ++q) pk[q] = f2bf((v[q]-mu)*rs*nw[q] + nb[q]);
      *(s16x4*)(a2 + SWZA(lane*8, rr) + rr*512) = pk;
    }
  }
  __syncthreads();

  int lr = lane & 31, lk = lane >> 5;
  int wn = wave;                      // 8 col-slices of 32

  f32x16 accO[2];
  #pragma unroll
  for (int i=0;i<2;++i)
    #pragma unroll
    for (int q=0;q<16;++q) accO[i][q] = 0.f;

  for (int ch = 0; ch < 4; ++ch) {
    f32x16 accH[2];
    #pragma unroll
    for (int i=0;i<2;++i)
      #pragma unroll
      for (int q=0;q<16;++q) accH[i][q] = 0.f;

    // ---- GEMM1: accH[64m][32n] = a2[64][256] @ W1-chunk ----
    const short* w1f = w1p + ((size_t)((ch*8 + wn)*16)*64 + lane)*8;
    bf16x8 bq[4];
    #pragma unroll
    for (int k = 0; k < 4; ++k) bq[k] = *(const bf16x8*)(w1f + (size_t)k*512);
    #pragma unroll
    for (int kk = 0; kk < 16; ++kk) {
      bf16x8 b = bq[kk & 3];
      if (kk < 12) bq[kk & 3] = *(const bf16x8*)(w1f + (size_t)(kk+4)*512);
      int kb = kk*32 + lk*16;
      bf16x8 a0 = *(const bf16x8*)(a2 + SWZA(kb, lr) + lr*512);
      bf16x8 a1 = *(const bf16x8*)(a2 + SWZA(kb, 32+lr) + (32+lr)*512);
      accH[0] = __builtin_amdgcn_mfma_f32_32x32x16_bf16(a0, b, accH[0], 0,0,0);
      accH[1] = __builtin_amdgcn_mfma_f32_32x32x16_bf16(a1, b, accH[1], 0,0,0);
    }

    // ---- bias + GeLU -> hc (bf16, swizzled) ----
    {
      float b1v = b1[ch*256 + wn*32 + lr];
      int colb = (wn*32 + lr)*2;
      #pragma unroll
      for (int ms = 0; ms < 2; ++ms) {
        #pragma unroll
        for (int r = 0; r < 16; ++r) {
          int rowl = ms*32 + (r&3) + 8*(r>>2) + 4*lk;
          float g = gelu_f(accH[ms][r] + b1v);
          *(short*)(hcb + SWZA(colb, rowl) + rowl*512) = f2bf(g);
        }
      }
    }
    __syncthreads();

    // ---- GEMM2: accO[64m][32n] += hc[64][256] @ W2-chunk ----
    const short* w2f = w2p + ((size_t)(wn*64 + ch*16)*64 + lane)*8;
    #pragma unroll
    for (int k = 0; k < 4; ++k) bq[k] = *(const bf16x8*)(w2f + (size_t)k*512);
    #pragma unroll
    for (int kk = 0; kk < 16; ++kk) {
      bf16x8 b = bq[kk & 3];
      if (kk < 12) bq[kk & 3] = *(const bf16x8*)(w2f + (size_t)(kk+4)*512);
      int kb = kk*32 + lk*16;
      bf16x8 a0 = *(const bf16x8*)(hcb + SWZA(kb, lr) + lr*512);
      bf16x8 a1 = *(const bf16x8*)(hcb + SWZA(kb, 32+lr) + (32+lr)*512);
      accO[0] = __builtin_amdgcn_mfma_f32_32x32x16_bf16(a0, b, accO[0], 0,0,0);
      accO[1] = __builtin_amdgcn_mfma_f32_32x32x16_bf16(a1, b, accO[1], 0,0,0);
    }
    __syncthreads();   // protect hc before next chunk's GeLU writes
  }

  // ---- epilogue: out = x1 + accO + b2 ----
  {
    int col = wn*32 + lr;
    float b2v = b2[col];
    #pragma unroll
    for (int ms = 0; ms < 2; ++ms) {
      #pragma unroll
      for (int r = 0; r < 16; ++r) {
        int row = ms*32 + (r&3) + 8*(r>>2) + 4*lk;
        size_t off = (size_t)(m0 + row)*256 + col;
        out[off] = x1[off] + accO[ms][r] + b2v;
      }
    }
  }
}

extern "C" void kernel_launch(void* const* d_in, const int* in_sizes, int n_in,
                              void* d_out, int out_size, void* d_ws, size_t ws_size,
                              hipStream_t stream) {
  const float* x    = (const float*)d_in[0];
  const float* n1w  = (const float*)d_in[1];
  const float* n1b  = (const float*)d_in[2];
  const float* spw  = (const float*)d_in[3];
  const float* spb  = (const float*)d_in[4];
  const float* n2w  = (const float*)d_in[5];
  const float* n2b  = (const float*)d_in[6];
  const float* fc1w = (const float*)d_in[7];
  const float* fc1b = (const float*)d_in[8];
  const float* fc2w = (const float*)d_in[9];
  const float* fc2b = (const float*)d_in[10];
  float* outp = (float*)d_out;

  char* ws = (char*)d_ws;
  short* w1p = (short*)ws;                    // 524288 B
  short* w2p = (short*)(ws + 524288);         // 524288 B
  f16x2* wsp2 = (f16x2*)(ws + 1048576);       // 8*25*52*4 = 41600 B

  prep_k<<<257, 256, 0, stream>>>(fc1w, fc2w, spw, w1p, w2p, wsp2);

  hipFuncSetAttribute(reinterpret_cast<const void*>(win_k),
                      hipFuncAttributeMaxDynamicSharedMemorySize, 102400);
  win_k<<<648, 512, 102400, stream>>>(x, n1w, n1b, spb, wsp2, outp);

  hipFuncSetAttribute(reinterpret_cast<const void*>(mlp_k),
                      hipFuncAttributeMaxDynamicSharedMemorySize, 65536);
  mlp_k<<<MTOT/64, 512, 65536, stream>>>(outp, outp, w1p, w2p, n2w, n2b, fc1b, fc2b);
}

// Round 6
// 334.072 us; speedup vs baseline: 1.7228x; 1.1342x over previous
//
#include <hip/hip_runtime.h>
#include <hip/hip_bf16.h>

#define NHEAD 8
#define IMG   3136      // 56*56
#define MTOT  100352    // 32*3136

typedef __attribute__((ext_vector_type(2))) _Float16 f16x2;
typedef __attribute__((ext_vector_type(8))) _Float16 f16x8;
typedef __attribute__((ext_vector_type(4))) float    f32x4;
typedef __attribute__((ext_vector_type(16))) float   f32x16;
typedef __attribute__((ext_vector_type(8))) short    bf16x8;
typedef __attribute__((ext_vector_type(4))) short    s16x4;
typedef __attribute__((ext_vector_type(4))) int      i32x4;

// swizzle for 512B rows: row bits 0-2 -> byte bits 4-6, row bit 3 -> byte bit 7
#define SWZA(byteoff, r) ((byteoff) ^ (((r)&7)<<4) ^ ((((r)>>3)&1)<<7))

__device__ __forceinline__ short f2bf(float f){
  union { float fv; unsigned u; } a; a.fv = f;
  unsigned u = a.u;
  unsigned r = (u + 0x7fffu + ((u >> 16) & 1u)) >> 16;
  return (short)r;
}

__device__ __forceinline__ float dot2f16(f16x2 a, f16x2 b, float c){
#if __has_builtin(__builtin_amdgcn_fdot2)
  return __builtin_amdgcn_fdot2(a, b, c, false);
#else
  return c + (float)a[0]*(float)b[0] + (float)a[1]*(float)b[1];
#endif
}

// fast tanh-form GeLU (max abs dev from exact erf-GeLU ~3e-4)
__device__ __forceinline__ float gelu_f(float v){
  float u = v*(0.7978845608028654f + 0.0356774081f*(v*v));
  float e = __expf(2.f*u);
  float th = 1.f - 2.f/(e + 1.f);
  return 0.5f*v*(1.f + th);
}

// ---------------- K0: weight prep ----------------
// blocks 0..127  : w1p fragment-packed  (fc1_w [256][1024] -> [(f*16+kk)*64+lane][8] bf16)
// blocks 128..255: w2p fragment-packed  (fc2_w [1024][256] -> [(f*64+kk)*64+lane][8] bf16)
// block 256      : spatial weight pack -> [h][jpp(25)][i(52 pad)] f16x2 of (j=2jpp, 2jpp+1)
__global__ void prep_k(const float* __restrict__ fc1w, const float* __restrict__ fc2w,
                       const float* __restrict__ spw,
                       short* __restrict__ w1p, short* __restrict__ w2p,
                       f16x2* __restrict__ wsp2)
{
  int bid = blockIdx.x, t = threadIdx.x;
  if (bid < 128) {
    int id = bid*256 + t;            // [0, 32768)
    int l = id & 63, fk = id >> 6;   // fk = f*16+kk
    int kk = fk & 15, f = fk >> 4;
    int n = f*32 + (l & 31);
    int kbase = kk*16 + (l >> 5)*8;
    bf16x8 o;
    #pragma unroll
    for (int e = 0; e < 8; ++e) o[e] = f2bf(fc1w[(size_t)(kbase+e)*1024 + n]);
    *(bf16x8*)(w1p + (size_t)id*8) = o;
  } else if (bid < 256) {
    int id = (bid-128)*256 + t;      // [0, 32768)
    int l = id & 63, fk = id >> 6;   // fk = f*64+kk
    int kk = fk & 63, f = fk >> 6;
    int n = f*32 + (l & 31);
    int kbase = kk*16 + (l >> 5)*8;
    bf16x8 o;
    #pragma unroll
    for (int e = 0; e < 8; ++e) o[e] = f2bf(fc2w[(size_t)(kbase+e)*256 + n]);
    *(bf16x8*)(w2p + (size_t)id*8) = o;
  } else {
    // 8 heads * 25 jpp * 52 i-slots
    for (int idx = t; idx < 8*25*52; idx += 256) {
      int h = idx / 1300, rem = idx - h*1300;
      int jpp = rem / 52, i = rem - jpp*52;
      float lo = 0.f, hi = 0.f;
      if (i < 49) {
        int j0 = jpp*2;
        lo = spw[(size_t)(h*49 + i)*49 + j0];
        if (j0 + 1 < 49) hi = spw[(size_t)(h*49 + i)*49 + j0 + 1];
      }
      f16x2 v; v[0] = (_Float16)lo; v[1] = (_Float16)hi;
      wsp2[idx] = v;
    }
  }
}

// ---------------- K1: LN1 + spatial window MLP + residual -> x1 (=d_out) ----------------
// 1296 blocks x 512 thr; 2 windows/block; wave = head; half-wave = window; 1 window/thread.
// Weights via wave-uniform pointer (scalar K$ loads). LDS: 2 x [25 jpp][256 c] f16x2 = 51200 B.
__global__ __launch_bounds__(512,4) void win_k(
    const float* __restrict__ x, const float* __restrict__ n1w, const float* __restrict__ n1b,
    const float* __restrict__ spb, const f16x2* __restrict__ wsp2,
    float* __restrict__ x1)
{
  extern __shared__ char wsm[];
  char* lx = wsm;                 // 51200
  int t = threadIdx.x, lane = t & 63, wave = t >> 6;
  int bid = blockIdx.x;

  int wi_[2], wj_[2], b_[2];
  #pragma unroll
  for (int w = 0; w < 2; ++w) {
    int win = bid*2 + w;
    b_[w] = win/81; int rem = win - b_[w]*81;
    wi_[w] = rem/9; wj_[w] = rem - (rem/9)*9;
  }

  // zero x-tile (covers padded positions + j=49 pad half)
  {
    i32x4 z4 = {0,0,0,0};
    i32x4* lx4 = (i32x4*)lx;
    for (int i = t; i < 3200; i += 512) lx4[i] = z4;
  }
  __syncthreads();

  // LN phase: 2 windows x 49 rows over 8 waves
  f32x4 wv = *(const f32x4*)(n1w + lane*4);
  f32x4 bv = *(const f32x4*)(n1b + lane*4);
  #pragma unroll
  for (int w = 0; w < 2; ++w) {
    for (int i = wave; i < 49; i += 8) {
      int iy = i/7, ix = i - iy*7;
      int hh = wi_[w]*7 + iy - 4, ww = wj_[w]*7 + ix - 4;
      if (hh < 0 || hh >= 56 || ww < 0 || ww >= 56) continue;  // wave-uniform
      const float* row = x + ((size_t)(b_[w]*IMG + hh*56 + ww))*256;
      f32x4 v = *(const f32x4*)(row + lane*4);
      float s  = v[0]+v[1]+v[2]+v[3];
      float s2 = v[0]*v[0]+v[1]*v[1]+v[2]*v[2]+v[3]*v[3];
      #pragma unroll
      for (int m = 1; m < 64; m <<= 1) { s += __shfl_xor(s, m); s2 += __shfl_xor(s2, m); }
      float mu = s * (1.f/256.f);
      float rs = rsqrtf(s2*(1.f/256.f) - mu*mu + 1e-5f);
      char* base = lx + w*25600 + (i>>1)*1024 + (i&1)*2;
      #pragma unroll
      for (int q = 0; q < 4; ++q)
        *(_Float16*)(base + (lane*4+q)*4) = (_Float16)(((v[q]-mu)*rs)*wv[q] + bv[q]);
    }
  }
  __syncthreads();

  // dot phase: wave = head h (uniform); half-wave = window; one window per thread
  int h = __builtin_amdgcn_readfirstlane(wave);
  int d = lane & 31;
  int w = lane >> 5;
  int c = h*32 + d;
  const char* lxW = lx + w*25600 + c*4;
  const char* wgh = (const char*)wsp2 + h*5200;   // uniform -> scalar loads

  float acc[52];
  #pragma unroll
  for (int i = 0; i < 52; ++i) acc[i] = 0.f;

  for (int jpp = 0; jpp < 25; ++jpp) {
    f16x2 xa = *(const f16x2*)(lxW + jpp*1024);
    const char* wrow = wgh + jpp*208;
    #pragma unroll
    for (int ib = 0; ib < 13; ++ib) {
      f16x8 wq = *(const f16x8*)(wrow + ib*16);
      #pragma unroll
      for (int q = 0; q < 4; ++q) {
        f16x2 wp; wp[0] = wq[2*q]; wp[1] = wq[2*q+1];
        acc[ib*4+q] = dot2f16(wp, xa, acc[ib*4+q]);
      }
    }
  }

  // epilogue: residual + bias (half-wave 128B contiguous stores)
  int winW = bid*2 + w;
  int bW = winW/81, remW = winW - bW*81, wiW = remW/9, wjW = remW - (remW/9)*9;
  #pragma unroll
  for (int i = 0; i < 49; ++i) {
    int iy = i/7, ix = i - iy*7;
    float sb = spb[h*49 + i];
    int hh = wiW*7 + iy - 4, ww = wjW*7 + ix - 4;
    if (hh >= 0 && hh < 56 && ww >= 0 && ww < 56) {
      size_t off = ((size_t)(bW*IMG + hh*56 + ww))*256 + c;
      x1[off] = x[off] + acc[i] + sb;
    }
  }
}

// ---------------- K2: fused LN2 + fc1 + GeLU + fc2 + residual (in-place on d_out) ----------------
// 1568 blocks x 512 thr (8 waves). 64-row tile. LDS: a2[64][512B] + hc[64][512B] = 64 KB
// -> 2 blocks/CU. Per wave: 64 rows x 32 cols, 1 B-frag/kk, depth-4 register prefetch.
__global__ __launch_bounds__(512,4) void mlp_k(
    const float* __restrict__ x1, float* __restrict__ out,
    const short* __restrict__ w1p, const short* __restrict__ w2p,
    const float* __restrict__ n2w, const float* __restrict__ n2b,
    const float* __restrict__ b1, const float* __restrict__ b2)
{
  extern __shared__ char sm[];
  char* a2  = sm;                 // 32768
  char* hcb = sm + 32768;         // 32768

  int t = threadIdx.x, lane = t & 63, wave = t >> 6;
  int m0 = blockIdx.x * 64;

  // ---- Phase A: LN2 of 64 rows -> a2 (bf16, swizzled) ----
  {
    f32x4 nw = *(const f32x4*)(n2w + lane*4);
    f32x4 nb = *(const f32x4*)(n2b + lane*4);
    #pragma unroll
    for (int rq = 0; rq < 8; ++rq) {
      int rr = wave*8 + rq;
      f32x4 v = *(const f32x4*)(x1 + (size_t)(m0+rr)*256 + lane*4);
      float s  = v[0]+v[1]+v[2]+v[3];
      float s2 = v[0]*v[0]+v[1]*v[1]+v[2]*v[2]+v[3]*v[3];
      #pragma unroll
      for (int m = 1; m < 64; m <<= 1){ s += __shfl_xor(s,m); s2 += __shfl_xor(s2,m); }
      float mu = s*(1.f/256.f);
      float rs = rsqrtf(s2*(1.f/256.f) - mu*mu + 1e-5f);
      s16x4 pk;
      #pragma unroll
      for (int q = 0; q < 4; ++q) pk[q] = f2bf((v[q]-mu)*rs*nw[q] + nb[q]);
      *(s16x4*)(a2 + SWZA(lane*8, rr) + rr*512) = pk;
    }
  }
  __syncthreads();

  int lr = lane & 31, lk = lane >> 5;
  int wn = wave;                      // 8 col-slices of 32

  f32x16 accO[2];
  #pragma unroll
  for (int i=0;i<2;++i)
    #pragma unroll
    for (int q=0;q<16;++q) accO[i][q] = 0.f;

  for (int ch = 0; ch < 4; ++ch) {
    f32x16 accH[2];
    #pragma unroll
    for (int i=0;i<2;++i)
      #pragma unroll
      for (int q=0;q<16;++q) accH[i][q] = 0.f;

    // ---- GEMM1: accH[64m][32n] = a2[64][256] @ W1-chunk ----
    const short* w1f = w1p + ((size_t)((ch*8 + wn)*16)*64 + lane)*8;
    bf16x8 bq[4];
    #pragma unroll
    for (int k = 0; k < 4; ++k) bq[k] = *(const bf16x8*)(w1f + (size_t)k*512);
    __builtin_amdgcn_s_setprio(1);
    #pragma unroll
    for (int kk = 0; kk < 16; ++kk) {
      bf16x8 b = bq[kk & 3];
      if (kk < 12) bq[kk & 3] = *(const bf16x8*)(w1f + (size_t)(kk+4)*512);
      int kb = kk*32 + lk*16;
      bf16x8 a0 = *(const bf16x8*)(a2 + SWZA(kb, lr) + lr*512);
      bf16x8 a1 = *(const bf16x8*)(a2 + SWZA(kb, 32+lr) + (32+lr)*512);
      accH[0] = __builtin_amdgcn_mfma_f32_32x32x16_bf16(a0, b, accH[0], 0,0,0);
      accH[1] = __builtin_amdgcn_mfma_f32_32x32x16_bf16(a1, b, accH[1], 0,0,0);
    }
    __builtin_amdgcn_s_setprio(0);

    // ---- bias + GeLU -> hc (bf16, swizzled) ----
    {
      float b1v = b1[ch*256 + wn*32 + lr];
      int colb = (wn*32 + lr)*2;
      #pragma unroll
      for (int ms = 0; ms < 2; ++ms) {
        #pragma unroll
        for (int r = 0; r < 16; ++r) {
          int rowl = ms*32 + (r&3) + 8*(r>>2) + 4*lk;
          float g = gelu_f(accH[ms][r] + b1v);
          *(short*)(hcb + SWZA(colb, rowl) + rowl*512) = f2bf(g);
        }
      }
    }
    __syncthreads();

    // ---- GEMM2: accO[64m][32n] += hc[64][256] @ W2-chunk ----
    const short* w2f = w2p + ((size_t)(wn*64 + ch*16)*64 + lane)*8;
    #pragma unroll
    for (int k = 0; k < 4; ++k) bq[k] = *(const bf16x8*)(w2f + (size_t)k*512);
    __builtin_amdgcn_s_setprio(1);
    #pragma unroll
    for (int kk = 0; kk < 16; ++kk) {
      bf16x8 b = bq[kk & 3];
      if (kk < 12) bq[kk & 3] = *(const bf16x8*)(w2f + (size_t)(kk+4)*512);
      int kb = kk*32 + lk*16;
      bf16x8 a0 = *(const bf16x8*)(hcb + SWZA(kb, lr) + lr*512);
      bf16x8 a1 = *(const bf16x8*)(hcb + SWZA(kb, 32+lr) + (32+lr)*512);
      accO[0] = __builtin_amdgcn_mfma_f32_32x32x16_bf16(a0, b, accO[0], 0,0,0);
      accO[1] = __builtin_amdgcn_mfma_f32_32x32x16_bf16(a1, b, accO[1], 0,0,0);
    }
    __builtin_amdgcn_s_setprio(0);
    __syncthreads();   // protect hc before next chunk's GeLU writes
  }

  // ---- epilogue: out = x1 + accO + b2 ----
  {
    int col = wn*32 + lr;
    float b2v = b2[col];
    #pragma unroll
    for (int ms = 0; ms < 2; ++ms) {
      #pragma unroll
      for (int r = 0; r < 16; ++r) {
        int row = ms*32 + (r&3) + 8*(r>>2) + 4*lk;
        size_t off = (size_t)(m0 + row)*256 + col;
        out[off] = x1[off] + accO[ms][r] + b2v;
      }
    }
  }
}

extern "C" void kernel_launch(void* const* d_in, const int* in_sizes, int n_in,
                              void* d_out, int out_size, void* d_ws, size_t ws_size,
                              hipStream_t stream) {
  const float* x    = (const float*)d_in[0];
  const float* n1w  = (const float*)d_in[1];
  const float* n1b  = (const float*)d_in[2];
  const float* spw  = (const float*)d_in[3];
  const float* spb  = (const float*)d_in[4];
  const float* n2w  = (const float*)d_in[5];
  const float* n2b  = (const float*)d_in[6];
  const float* fc1w = (const float*)d_in[7];
  const float* fc1b = (const float*)d_in[8];
  const float* fc2w = (const float*)d_in[9];
  const float* fc2b = (const float*)d_in[10];
  float* outp = (float*)d_out;

  char* ws = (char*)d_ws;
  short* w1p = (short*)ws;                    // 524288 B
  short* w2p = (short*)(ws + 524288);         // 524288 B
  f16x2* wsp2 = (f16x2*)(ws + 1048576);       // 8*25*52*4 = 41600 B

  prep_k<<<257, 256, 0, stream>>>(fc1w, fc2w, spw, w1p, w2p, wsp2);

  hipFuncSetAttribute(reinterpret_cast<const void*>(win_k),
                      hipFuncAttributeMaxDynamicSharedMemorySize, 51200);
  win_k<<<1296, 512, 51200, stream>>>(x, n1w, n1b, spb, wsp2, outp);

  hipFuncSetAttribute(reinterpret_cast<const void*>(mlp_k),
                      hipFuncAttributeMaxDynamicSharedMemorySize, 65536);
  mlp_k<<<MTOT/64, 512, 65536, stream>>>(outp, outp, w1p, w2p, n2w, n2b, fc1b, fc2b);
}

// Round 7
// 318.708 us; speedup vs baseline: 1.8058x; 1.0482x over previous
//
#include <hip/hip_runtime.h>
#include <hip/hip_bf16.h>

#define NHEAD 8
#define IMG   3136      // 56*56
#define MTOT  100352    // 32*3136

typedef __attribute__((ext_vector_type(2))) _Float16 f16x2;
typedef __attribute__((ext_vector_type(8))) _Float16 f16x8;
typedef __attribute__((ext_vector_type(4))) float    f32x4;
typedef __attribute__((ext_vector_type(16))) float   f32x16;
typedef __attribute__((ext_vector_type(8))) short    bf16x8;
typedef __attribute__((ext_vector_type(4))) short    s16x4;
typedef __attribute__((ext_vector_type(4))) int      i32x4;

// swizzle: row bits 0-2 -> byte bits 4-6, row bit 3 -> byte bit 7 (rows up to 512B; bijective)
#define SWZA(byteoff, r) ((byteoff) ^ (((r)&7)<<4) ^ ((((r)>>3)&1)<<7))

__device__ __forceinline__ short f2bf(float f){
  union { float fv; unsigned u; } a; a.fv = f;
  unsigned u = a.u;
  unsigned r = (u + 0x7fffu + ((u >> 16) & 1u)) >> 16;
  return (short)r;
}

// fast tanh-form GeLU (max abs dev from exact erf-GeLU ~3e-4)
__device__ __forceinline__ float gelu_f(float v){
  float u = v*(0.7978845608028654f + 0.0356774081f*(v*v));
  float e = __expf(2.f*u);
  float th = 1.f - 2.f/(e + 1.f);
  return 0.5f*v*(1.f + th);
}

// ---------------- K0: weight prep ----------------
// blocks 0..127  : w1p fragment-packed  (fc1_w [256][1024] -> [(f*16+kk)*64+lane][8] bf16)
// blocks 128..255: w2p fragment-packed  (fc2_w [1024][256] -> [(f*64+kk)*64+lane][8] bf16)
// block 256      : spatial W -> MFMA A-frag pack wspA[h][mt][kt][lane][8] bf16 (i,j zero-padded)
__global__ void prep_k(const float* __restrict__ fc1w, const float* __restrict__ fc2w,
                       const float* __restrict__ spw,
                       short* __restrict__ w1p, short* __restrict__ w2p,
                       short* __restrict__ wspA)
{
  int bid = blockIdx.x, t = threadIdx.x;
  if (bid < 128) {
    int id = bid*256 + t;            // [0, 32768)
    int l = id & 63, fk = id >> 6;   // fk = f*16+kk
    int kk = fk & 15, f = fk >> 4;
    int n = f*32 + (l & 31);
    int kbase = kk*16 + (l >> 5)*8;
    bf16x8 o;
    #pragma unroll
    for (int e = 0; e < 8; ++e) o[e] = f2bf(fc1w[(size_t)(kbase+e)*1024 + n]);
    *(bf16x8*)(w1p + (size_t)id*8) = o;
  } else if (bid < 256) {
    int id = (bid-128)*256 + t;      // [0, 32768)
    int l = id & 63, fk = id >> 6;   // fk = f*64+kk
    int kk = fk & 63, f = fk >> 6;
    int n = f*32 + (l & 31);
    int kbase = kk*16 + (l >> 5)*8;
    bf16x8 o;
    #pragma unroll
    for (int e = 0; e < 8; ++e) o[e] = f2bf(fc2w[(size_t)(kbase+e)*256 + n]);
    *(bf16x8*)(w2p + (size_t)id*8) = o;
  } else {
    // 4096 fragment-chunks: idx = ((h*2+mt)*4+kt)*64 + lane
    #pragma unroll
    for (int k = 0; k < 16; ++k) {
      int idx = t + k*256;
      int lane = idx & 63;
      int kt = (idx >> 6) & 3;
      int mt = (idx >> 8) & 1;
      int h  = idx >> 9;
      int i  = mt*32 + (lane & 31);
      int jb = kt*16 + (lane >> 5)*8;
      bf16x8 o;
      #pragma unroll
      for (int e = 0; e < 8; ++e) {
        int j = jb + e;
        float v = (i < 49 && j < 49) ? spw[(size_t)(h*49 + i)*49 + j] : 0.f;
        o[e] = f2bf(v);
      }
      *(bf16x8*)(wspA + (size_t)idx*8) = o;
    }
  }
}

// ---------------- K1: LN1 + spatial window MLP (MFMA) + residual -> x1 (=d_out) ----------------
// 1296 blocks x 512 thr; 2 windows/block; wave = head. LDS: lxT 64 KB + murs ~0.9 KB -> 2 blk/CU.
// Per wave: 8 A-frag global loads (packed W, L2-hot) + 8 LDS B-reads + 16 MFMA 32x32x16.
__global__ __launch_bounds__(512,4) void win_k(
    const float* __restrict__ x, const float* __restrict__ n1w, const float* __restrict__ n1b,
    const float* __restrict__ spb, const short* __restrict__ wspA,
    float* __restrict__ x1)
{
  extern __shared__ char wsm[];
  char*  lxT  = wsm;                      // 65536: row c (256 rows x 256B); byte7 = win, swizzled
  float* murs = (float*)(wsm + 65536);    // [2][56][2] f32
  int t = threadIdx.x, lane = t & 63, wave = t >> 6;
  int bid = blockIdx.x;

  // ---- LN stats: mu/rs per (win, pixel) ----
  #pragma unroll
  for (int w = 0; w < 2; ++w) {
    int win = bid*2 + w;
    int b = win/81, rem = win - b*81, wi = rem/9, wj = rem - (rem/9)*9;
    for (int i = wave; i < 49; i += 8) {
      int iy = i/7, ix = i - iy*7;
      int hh = wi*7 + iy - 4, ww = wj*7 + ix - 4;
      if (hh < 0 || hh >= 56 || ww < 0 || ww >= 56) continue;  // wave-uniform
      const float* row = x + ((size_t)(b*IMG + hh*56 + ww))*256;
      f32x4 v = *(const f32x4*)(row + lane*4);
      float s  = v[0]+v[1]+v[2]+v[3];
      float s2 = v[0]*v[0]+v[1]*v[1]+v[2]*v[2]+v[3]*v[3];
      #pragma unroll
      for (int m = 1; m < 64; m <<= 1) { s += __shfl_xor(s, m); s2 += __shfl_xor(s2, m); }
      float mu = s * (1.f/256.f);
      float rs = rsqrtf(s2*(1.f/256.f) - mu*mu + 1e-5f);
      if (lane == 0) { murs[(w*56+i)*2] = mu; murs[(w*56+i)*2+1] = rs; }
    }
  }
  __syncthreads();

  // ---- pass2: thread = (win, c); column-read x, LN-apply, write x^T bf16 into lxT ----
  {
    int w = t >> 8, c = t & 255;
    int win = bid*2 + w;
    int b = win/81, rem = win - b*81, wi = rem/9, wj = rem - (rem/9)*9;
    float nwc = n1w[c], nbc = n1b[c];
    char* rowb = lxT + c*256;
    #pragma unroll
    for (int cj = 0; cj < 7; ++cj) {
      bf16x8 pk;
      #pragma unroll
      for (int e = 0; e < 8; ++e) {
        int p = cj*8 + e;                 // compile-time
        short val = 0;
        if (p < 49) {
          int iy = p/7, ix = p - iy*7;    // compile-time
          int hh = wi*7 + iy - 4, ww = wj*7 + ix - 4;
          if (hh >= 0 && hh < 56 && ww >= 0 && ww < 56) {   // wave-uniform
            float mu = murs[(w*56+p)*2], rs = murs[(w*56+p)*2+1];
            float xv = x[((size_t)(b*IMG + hh*56 + ww))*256 + c];
            val = f2bf((xv - mu)*rs*nwc + nbc);
          }
        }
        pk[e] = val;
      }
      *(bf16x8*)(rowb + SWZA(w*128 + cj*16, c)) = pk;
    }
    bf16x8 z = {0,0,0,0,0,0,0,0};
    *(bf16x8*)(rowb + SWZA(w*128 + 112, c)) = z;   // j 56..63 pad
  }
  __syncthreads();

  // ---- MFMA dot: wave = head; 2 windows; i-tiles mt=0,1; K=49(pad 64) over 4 kt ----
  int h = wave, d = lane & 31, lk = lane >> 5;
  const short* wA = wspA + h*4096;
  int c = h*32 + d;
  f32x16 a00, a01, a10, a11;   // [mt][win]
  #pragma unroll
  for (int q = 0; q < 16; ++q) { a00[q]=0.f; a01[q]=0.f; a10[q]=0.f; a11[q]=0.f; }
  #pragma unroll
  for (int kt = 0; kt < 4; ++kt) {
    bf16x8 A0 = *(const bf16x8*)(wA + (kt*64 + lane)*8);
    bf16x8 A1 = *(const bf16x8*)(wA + ((4+kt)*64 + lane)*8);
    int bo = kt*32 + lk*16;
    bf16x8 B0 = *(const bf16x8*)(lxT + c*256 + SWZA(bo, c));
    bf16x8 B1 = *(const bf16x8*)(lxT + c*256 + SWZA(128 + bo, c));
    a00 = __builtin_amdgcn_mfma_f32_32x32x16_bf16(A0, B0, a00, 0,0,0);
    a10 = __builtin_amdgcn_mfma_f32_32x32x16_bf16(A1, B0, a10, 0,0,0);
    a01 = __builtin_amdgcn_mfma_f32_32x32x16_bf16(A0, B1, a01, 0,0,0);
    a11 = __builtin_amdgcn_mfma_f32_32x32x16_bf16(A1, B1, a11, 0,0,0);
  }

  // ---- epilogue: x1 = x + spatial + bias ----
  #pragma unroll
  for (int w = 0; w < 2; ++w) {
    int win = bid*2 + w;
    int b = win/81, rem = win - b*81, wi = rem/9, wj = rem - (rem/9)*9;
    #pragma unroll
    for (int mt = 0; mt < 2; ++mt) {
      #pragma unroll
      for (int r = 0; r < 16; ++r) {
        int i = mt*32 + (r&3) + 8*(r>>2) + 4*lk;
        if (i < 49) {
          int iy = i/7, ix = i - iy*7;
          int hh = wi*7 + iy - 4, ww = wj*7 + ix - 4;
          if (hh >= 0 && hh < 56 && ww >= 0 && ww < 56) {
            size_t off = ((size_t)(b*IMG + hh*56 + ww))*256 + c;
            float av = mt==0 ? (w==0 ? a00[r] : a01[r]) : (w==0 ? a10[r] : a11[r]);
            x1[off] = x[off] + av + spb[h*49 + i];
          }
        }
      }
    }
  }
}

// ---------------- K2: fused LN2 + fc1 + GeLU + fc2 + residual (in-place on d_out) ----------------
// 1568 blocks x 512 thr (8 waves). 64-row tile. LDS: a2[64][512B] + hc[64][512B] = 64 KB
// -> 2 blocks/CU. Per wave: 64 rows x 32 cols, 1 B-frag/kk, depth-4 register prefetch.
__global__ __launch_bounds__(512,4) void mlp_k(
    const float* __restrict__ x1, float* __restrict__ out,
    const short* __restrict__ w1p, const short* __restrict__ w2p,
    const float* __restrict__ n2w, const float* __restrict__ n2b,
    const float* __restrict__ b1, const float* __restrict__ b2)
{
  extern __shared__ char sm[];
  char* a2  = sm;                 // 32768
  char* hcb = sm + 32768;         // 32768

  int t = threadIdx.x, lane = t & 63, wave = t >> 6;
  int m0 = blockIdx.x * 64;

  // ---- Phase A: LN2 of 64 rows -> a2 (bf16, swizzled) ----
  {
    f32x4 nw = *(const f32x4*)(n2w + lane*4);
    f32x4 nb = *(const f32x4*)(n2b + lane*4);
    #pragma unroll
    for (int rq = 0; rq < 8; ++rq) {
      int rr = wave*8 + rq;
      f32x4 v = *(const f32x4*)(x1 + (size_t)(m0+rr)*256 + lane*4);
      float s  = v[0]+v[1]+v[2]+v[3];
      float s2 = v[0]*v[0]+v[1]*v[1]+v[2]*v[2]+v[3]*v[3];
      #pragma unroll
      for (int m = 1; m < 64; m <<= 1){ s += __shfl_xor(s,m); s2 += __shfl_xor(s2,m); }
      float mu = s*(1.f/256.f);
      float rs = rsqrtf(s2*(1.f/256.f) - mu*mu + 1e-5f);
      s16x4 pk;
      #pragma unroll
      for (int q = 0; q < 4; ++q) pk[q] = f2bf((v[q]-mu)*rs*nw[q] + nb[q]);
      *(s16x4*)(a2 + SWZA(lane*8, rr) + rr*512) = pk;
    }
  }
  __syncthreads();

  int lr = lane & 31, lk = lane >> 5;
  int wn = wave;                      // 8 col-slices of 32

  f32x16 accO[2];
  #pragma unroll
  for (int i=0;i<2;++i)
    #pragma unroll
    for (int q=0;q<16;++q) accO[i][q] = 0.f;

  for (int ch = 0; ch < 4; ++ch) {
    f32x16 accH[2];
    #pragma unroll
    for (int i=0;i<2;++i)
      #pragma unroll
      for (int q=0;q<16;++q) accH[i][q] = 0.f;

    // ---- GEMM1: accH[64m][32n] = a2[64][256] @ W1-chunk ----
    const short* w1f = w1p + ((size_t)((ch*8 + wn)*16)*64 + lane)*8;
    bf16x8 bq[4];
    #pragma unroll
    for (int k = 0; k < 4; ++k) bq[k] = *(const bf16x8*)(w1f + (size_t)k*512);
    __builtin_amdgcn_s_setprio(1);
    #pragma unroll
    for (int kk = 0; kk < 16; ++kk) {
      bf16x8 b = bq[kk & 3];
      if (kk < 12) bq[kk & 3] = *(const bf16x8*)(w1f + (size_t)(kk+4)*512);
      int kb = kk*32 + lk*16;
      bf16x8 a0 = *(const bf16x8*)(a2 + SWZA(kb, lr) + lr*512);
      bf16x8 a1 = *(const bf16x8*)(a2 + SWZA(kb, 32+lr) + (32+lr)*512);
      accH[0] = __builtin_amdgcn_mfma_f32_32x32x16_bf16(a0, b, accH[0], 0,0,0);
      accH[1] = __builtin_amdgcn_mfma_f32_32x32x16_bf16(a1, b, accH[1], 0,0,0);
    }
    __builtin_amdgcn_s_setprio(0);

    // ---- bias + GeLU -> hc (bf16, swizzled) ----
    {
      float b1v = b1[ch*256 + wn*32 + lr];
      int colb = (wn*32 + lr)*2;
      #pragma unroll
      for (int ms = 0; ms < 2; ++ms) {
        #pragma unroll
        for (int r = 0; r < 16; ++r) {
          int rowl = ms*32 + (r&3) + 8*(r>>2) + 4*lk;
          float g = gelu_f(accH[ms][r] + b1v);
          *(short*)(hcb + SWZA(colb, rowl) + rowl*512) = f2bf(g);
        }
      }
    }
    __syncthreads();

    // ---- GEMM2: accO[64m][32n] += hc[64][256] @ W2-chunk ----
    const short* w2f = w2p + ((size_t)(wn*64 + ch*16)*64 + lane)*8;
    #pragma unroll
    for (int k = 0; k < 4; ++k) bq[k] = *(const bf16x8*)(w2f + (size_t)k*512);
    __builtin_amdgcn_s_setprio(1);
    #pragma unroll
    for (int kk = 0; kk < 16; ++kk) {
      bf16x8 b = bq[kk & 3];
      if (kk < 12) bq[kk & 3] = *(const bf16x8*)(w2f + (size_t)(kk+4)*512);
      int kb = kk*32 + lk*16;
      bf16x8 a0 = *(const bf16x8*)(hcb + SWZA(kb, lr) + lr*512);
      bf16x8 a1 = *(const bf16x8*)(hcb + SWZA(kb, 32+lr) + (32+lr)*512);
      accO[0] = __builtin_amdgcn_mfma_f32_32x32x16_bf16(a0, b, accO[0], 0,0,0);
      accO[1] = __builtin_amdgcn_mfma_f32_32x32x16_bf16(a1, b, accO[1], 0,0,0);
    }
    __builtin_amdgcn_s_setprio(0);
    __syncthreads();   // protect hc before next chunk's GeLU writes
  }

  // ---- epilogue: out = x1 + accO + b2 ----
  {
    int col = wn*32 + lr;
    float b2v = b2[col];
    #pragma unroll
    for (int ms = 0; ms < 2; ++ms) {
      #pragma unroll
      for (int r = 0; r < 16; ++r) {
        int row = ms*32 + (r&3) + 8*(r>>2) + 4*lk;
        size_t off = (size_t)(m0 + row)*256 + col;
        out[off] = x1[off] + accO[ms][r] + b2v;
      }
    }
  }
}

extern "C" void kernel_launch(void* const* d_in, const int* in_sizes, int n_in,
                              void* d_out, int out_size, void* d_ws, size_t ws_size,
                              hipStream_t stream) {
  const float* x    = (const float*)d_in[0];
  const float* n1w  = (const float*)d_in[1];
  const float* n1b  = (const float*)d_in[2];
  const float* spw  = (const float*)d_in[3];
  const float* spb  = (const float*)d_in[4];
  const float* n2w  = (const float*)d_in[5];
  const float* n2b  = (const float*)d_in[6];
  const float* fc1w = (const float*)d_in[7];
  const float* fc1b = (const float*)d_in[8];
  const float* fc2w = (const float*)d_in[9];
  const float* fc2b = (const float*)d_in[10];
  float* outp = (float*)d_out;

  char* ws = (char*)d_ws;
  short* w1p  = (short*)ws;                   // 524288 B
  short* w2p  = (short*)(ws + 524288);        // 524288 B
  short* wspA = (short*)(ws + 1048576);       // 65536 B: spatial W A-frag pack

  prep_k<<<257, 256, 0, stream>>>(fc1w, fc2w, spw, w1p, w2p, wspA);

  hipFuncSetAttribute(reinterpret_cast<const void*>(win_k),
                      hipFuncAttributeMaxDynamicSharedMemorySize, 66432);
  win_k<<<1296, 512, 66432, stream>>>(x, n1w, n1b, spb, wspA, outp);

  hipFuncSetAttribute(reinterpret_cast<const void*>(mlp_k),
                      hipFuncAttributeMaxDynamicSharedMemorySize, 65536);
  mlp_k<<<MTOT/64, 512, 65536, stream>>>(outp, outp, w1p, w2p, n2w, n2b, fc1b, fc2b);
}